// Round 12
// baseline (41.357 us; speedup 1.0000x reference)
//
#include <hip/hip_runtime.h>
#include <math.h>

#define TWO_PI_F 6.28318530717958647692f

typedef unsigned int u32;
typedef __attribute__((ext_vector_type(4))) float    f4;
typedef __attribute__((ext_vector_type(2))) float    f2;
typedef __attribute__((ext_vector_type(4))) _Float16 h4;
typedef __attribute__((ext_vector_type(8))) _Float16 h8;

union B8 { h8 v; h4 q[2]; };

// ---------------------------------------------------------------------------
// MFMA formulation. Hidden pre-activations are a K=16 matmul:
//   p(ij, h) = sum_k F[ij,k] * V[k,h]
//   F[ij,:] = [pe_roleA(4) | pe_roleB(4) | ct st 1 0 | 0-pad to 32]
//   V[k,h]  = [W1[0:4,h] | W1[4:8,h] | wc ws zc 0 | 0]   (zc = b1 + z@W1[10:42])
// Computed as C[h, ij] = A(h,k) x B(k, ij) with mfma_f32_16x16x32_f16:
//   A-frag: lane m=l&15 -> h, k-octet = l>>4 (zeros for k>=11 kill B garbage)
//   B-frag: lane n=l&15 -> ij, k-octet = l>>4, gathered from pe/P2 LDS tables
//   C: col=lane&15=ij, row=4*(l>>4)+reg=h  [m89-verified layout]
// Then VALU does only relu * (0.5*w2) and a 2-step shfl_xor h-reduction.
// 2048 ij-rows per 32x32 tile = both orientations; S[o][il][jl] in LDS gives
// the symmetrized output and the mirror tile without transposition.
// 2080 upper-triangular blocks, 256 threads.
// ---------------------------------------------------------------------------
__global__ __launch_bounds__(256, 4) void gd_mfma(
    const float* __restrict__ z,  const float* __restrict__ s,
    const float* __restrict__ W1, const float* __restrict__ b1,
    const float* __restrict__ W2, const float* __restrict__ b2v,
    float* __restrict__ out, int N, int NB)
{
    __shared__ __attribute__((aligned(16))) _Float16 Ald[64][32]; // 4KB   V^T rows
    __shared__ __attribute__((aligned(16))) h4 peb[64];           // 512B  pe rows f16
    __shared__ __attribute__((aligned(16))) h4 P2[1024];          // 8KB   {ct,st,1,0}
    __shared__ __attribute__((aligned(16))) float S[2][32][36];   // 9.2KB per-orient sums
    __shared__ f2 strig[64];                                      // 512B  {c1,s1} f32

    // --- triangular block decode: u -> (bi, bj), bj >= bi ---
    int u = blockIdx.x;
    int M = 2 * NB + 1;
    float disc = (float)(M * M - 8 * u);
    int bi = (int)(((float)M - sqrtf(disc)) * 0.5f);
    if (bi < 0) bi = 0;
    if (bi > NB - 1) bi = NB - 1;
    while (bi > 0 && bi * (M - bi) / 2 > u) --bi;
    while ((bi + 1) * (M - (bi + 1)) / 2 <= u) ++bi;
    int bj = bi + (u - bi * (M - bi) / 2);

    int t    = threadIdx.x;
    int lane = t & 63;

    // --- setup (t<64): trig tables + A (weight) rows ---
    if (t < 64) {
        int grow = (t < 32) ? (bi * 32 + t) : (bj * 32 + (t - 32));
        float ang = TWO_PI_F * s[grow];
        float c1 = __cosf(ang), s1 = __sinf(ang);
        float c2 = c1 * c1 - s1 * s1, s2 = 2.0f * c1 * s1;
        strig[t] = (f2){c1, s1};
        peb[t]   = (h4){(_Float16)c1, (_Float16)s1, (_Float16)c2, (_Float16)s2};

        float zc = b1[t];
#pragma unroll
        for (int zz = 0; zz < 32; ++zz)
            zc = fmaf(z[zz], W1[(10 + zz) * 64 + t], zc);

        h8 row0, row1;
#pragma unroll
        for (int k = 0; k < 8; ++k) row0[k] = (_Float16)W1[k * 64 + t];
        row1 = (h8)0;
        row1[0] = (_Float16)W1[8 * 64 + t];   // wc
        row1[1] = (_Float16)W1[9 * 64 + t];   // ws
        row1[2] = (_Float16)zc;               // bias via "1" feature
        *(h8*)&Ald[t][0]  = row0;
        *(h8*)&Ald[t][8]  = row1;
        *(h8*)&Ald[t][16] = (h8)0;            // k=16..31 zero: kills B garbage
        *(h8*)&Ald[t][24] = (h8)0;
    }
    __syncthreads();

    // --- P2 build (4 cells/thread) + per-wave A-frag/w2 register loads ---
    {
        int base = t * 4;
        int il = base >> 5, j0 = base & 31;
        f2 ci = strig[il];
#pragma unroll
        for (int c = 0; c < 4; ++c) {
            f2 cj = strig[32 + j0 + c];
            float ctv = fmaf(ci.x, cj.x, ci.y * cj.y);             // cos(2pi*dist)
            float stv = fabsf(fmaf(ci.y, cj.x, -(ci.x * cj.y)));   // sin(2pi*dist)
            P2[base + c] = (h4){(_Float16)ctv, (_Float16)stv,
                                (_Float16)1.0f, (_Float16)0.0f};
        }
    }

    h8 afr[4];
    f4 w2v[4];
#pragma unroll
    for (int m = 0; m < 4; ++m) {
        int h = m * 16 + (lane & 15);
        afr[m] = *(const h8*)&Ald[h][(lane >> 4) * 8];
        f4 w = *(const f4*)(W2 + m * 16 + (lane >> 4) * 4);
        w2v[m] = w * 0.5f;                    // fold symmetrization
    }
    __syncthreads();

    // --- phase 2: MFMA over 128 ij-tiles (2 orientations x 64 row-blocks) ---
    int wv = t >> 6;   // wave id 0..3
    int q  = lane >> 4;
#pragma unroll 4
    for (int i = 0; i < 32; ++i) {
        int tl  = wv * 32 + i;
        int o   = tl >> 6;                 // orientation
        int rb  = tl & 63;                 // 16-row block within 1024
        int idx = rb * 16 + (lane & 15);   // ij cell 0..1023
        int il  = idx >> 5, jl = idx & 31;

        int rA = o ? (32 + jl) : il;       // role-A pe row
        int rB = o ? il : (32 + jl);       // role-B pe row

        const h4* a1 = (q == 0) ? &peb[rA] : ((q == 1) ? &P2[idx] : &peb[0]);
        const h4* a2 = (q == 0) ? &peb[rB] : &peb[0];

        B8 bfr;
        bfr.q[0] = *a1;
        bfr.q[1] = *a2;

        f4 acc0 = __builtin_amdgcn_mfma_f32_16x16x32_f16(afr[0], bfr.v, (f4)(0.0f), 0, 0, 0);
        f4 acc1 = __builtin_amdgcn_mfma_f32_16x16x32_f16(afr[1], bfr.v, (f4)(0.0f), 0, 0, 0);
        f4 acc2 = __builtin_amdgcn_mfma_f32_16x16x32_f16(afr[2], bfr.v, (f4)(0.0f), 0, 0, 0);
        f4 acc3 = __builtin_amdgcn_mfma_f32_16x16x32_f16(afr[3], bfr.v, (f4)(0.0f), 0, 0, 0);

        float ps = 0.0f;
#pragma unroll
        for (int e = 0; e < 4; ++e) {
            ps = fmaf(fmaxf(acc0[e], 0.0f), w2v[0][e], ps);
            ps = fmaf(fmaxf(acc1[e], 0.0f), w2v[1][e], ps);
            ps = fmaf(fmaxf(acc2[e], 0.0f), w2v[2][e], ps);
            ps = fmaf(fmaxf(acc3[e], 0.0f), w2v[3][e], ps);
        }
        ps += __shfl_xor(ps, 16);           // sum h across lane groups
        ps += __shfl_xor(ps, 32);
        if ((lane & 48) == 0) S[o][il][jl] = ps;
    }
    __syncthreads();

    // --- phase 3: symmetrized output + mirror (coalesced f4 stores) ---
    float b2 = b2v[0];
    {
        int il = t >> 3;
        int j0 = (t & 7) * 4;
        f4 a = *(const f4*)&S[0][il][j0];
        f4 b = *(const f4*)&S[1][il][j0];
        f4 v;
#pragma unroll
        for (int c = 0; c < 4; ++c) {
            float x = a[c] + b[c] + b2;
            if (bi == bj && il == j0 + c) x = -1e9f;
            v[c] = x;
        }
        *(f4*)&out[(size_t)(bi * 32 + il) * N + bj * 32 + j0] = v;

        if (bj > bi) {
            int jl = t >> 3;
            int i0 = (t & 7) * 4;
            f4 m;
#pragma unroll
            for (int c = 0; c < 4; ++c)
                m[c] = S[0][i0 + c][jl] + S[1][i0 + c][jl] + b2;
            *(f4*)&out[(size_t)(bj * 32 + jl) * N + bi * 32 + i0] = m;
        }
    }
}

extern "C" void kernel_launch(void* const* d_in, const int* in_sizes, int n_in,
                              void* d_out, int out_size, void* d_ws, size_t ws_size,
                              hipStream_t stream) {
    const float* z  = (const float*)d_in[0];  // [32]
    const float* s  = (const float*)d_in[1];  // [N]
    const float* W1 = (const float*)d_in[2];  // [42,64]
    const float* b1 = (const float*)d_in[3];  // [64]
    const float* W2 = (const float*)d_in[4];  // [64]
    const float* b2 = (const float*)d_in[5];  // [1]
    int N = in_sizes[1];                      // 2048

    float* out = (float*)d_out;
    int NB = N / 32;
    int nblk = NB * (NB + 1) / 2;             // 2080 for N=2048
    gd_mfma<<<nblk, 256, 0, stream>>>(z, s, W1, b1, W2, b2, out, N, NB);
}

// Round 14
// 29.052 us; speedup vs baseline: 1.4236x; 1.4236x over previous
//
#include <hip/hip_runtime.h>
#include <math.h>

#define TWO_PI_F 6.28318530717958647692f

typedef unsigned int u32;
typedef __attribute__((ext_vector_type(4))) float    f4;
typedef __attribute__((ext_vector_type(16))) float   f16v;
typedef __attribute__((ext_vector_type(2))) float    f2;
typedef __attribute__((ext_vector_type(2))) _Float16 h2;
typedef __attribute__((ext_vector_type(4))) _Float16 h4;
typedef __attribute__((ext_vector_type(8))) _Float16 h8;

union B8 { h8 v; h4 q[2]; };

#if __has_builtin(__builtin_amdgcn_fdot2)
#define FDOT2(a, b, c) __builtin_amdgcn_fdot2((a), (b), (c), false)
#else
__device__ __forceinline__ float FDOT2(h2 a, h2 b, float c) {
    return c + (float)a[0] * (float)b[0] + (float)a[1] * (float)b[1];
}
#endif

#if __has_builtin(__builtin_amdgcn_cvt_pkrtz)
__device__ __forceinline__ h2 CVTPK(float a, float b) {
    return __builtin_bit_cast(h2, __builtin_amdgcn_cvt_pkrtz(a, b));
}
#else
__device__ __forceinline__ h2 CVTPK(float a, float b) {
    return (h2){(_Float16)a, (_Float16)b};
}
#endif

// ---------------------------------------------------------------------------
// MFMA formulation, 32x32x16 (K=16 exact, no padding waste):
//   p(h, v) = sum_k V[k,h] * F[v,k],  v = 1024 cells x 2 orientations
//   F[v,:] = [pe_roleA(4) | pe_roleB(4) | ct st 1 0 0 0 0 0]
//   A-frag (V^T): lane m=l&31 -> h(+32H), k-octet l>>5
//   B-frag (F):   lane n=l&31 -> v,       k-octet l>>5 (q=0: pe pair, q=1: P2)
//   C: col=lane&31 = v, row=(reg&3)+8*(reg>>2)+4*(lane>>5)  [m74/m101]
// Epilogue: packed cvt_pkrtz + pk_max + fdot2 (3 ops / h-pair), w2 pre-paired
// to match the C row layout. 2080 upper-triangular blocks, 256 threads.
// ---------------------------------------------------------------------------
__global__ __launch_bounds__(256, 4) void gd_mfma(
    const float* __restrict__ z,  const float* __restrict__ s,
    const float* __restrict__ W1, const float* __restrict__ b1,
    const float* __restrict__ W2, const float* __restrict__ b2v,
    float* __restrict__ out, int N, int NB)
{
    __shared__ __attribute__((aligned(16))) _Float16 Ald[64][24]; // 3KB, 48B rows (pad)
    __shared__ __attribute__((aligned(16))) h4 peb[64];           // 512B pe rows
    __shared__ __attribute__((aligned(16))) h4 P2[1024];          // 8KB {ct,st,1,0}
    __shared__ __attribute__((aligned(16))) h2 w2p[32];           // 128B paired 0.5*w2
    __shared__ __attribute__((aligned(16))) float S[2][32][36];   // 9.2KB
    __shared__ f2 strig[64];
    __shared__ h4 zq;

    // --- triangular block decode: u -> (bi, bj), bj >= bi ---
    int u = blockIdx.x;
    int M = 2 * NB + 1;
    float disc = (float)(M * M - 8 * u);
    int bi = (int)(((float)M - sqrtf(disc)) * 0.5f);
    if (bi < 0) bi = 0;
    if (bi > NB - 1) bi = NB - 1;
    while (bi > 0 && bi * (M - bi) / 2 > u) --bi;
    while ((bi + 1) * (M - (bi + 1)) / 2 <= u) ++bi;
    int bj = bi + (u - bi * (M - bi) / 2);

    int t    = threadIdx.x;
    int lane = t & 63;

    if (t == 0) zq = (h4)0;
    if (t >= 64 && t < 96) {             // paired 0.5*w2
        int r2 = t - 64;
        w2p[r2] = (h2){(_Float16)(0.5f * W2[2 * r2]),
                       (_Float16)(0.5f * W2[2 * r2 + 1])};
    }
    if (t < 64) {                        // trig + pe + V^T rows
        int grow = (t < 32) ? (bi * 32 + t) : (bj * 32 + (t - 32));
        float ang = TWO_PI_F * s[grow];
        float c1 = __cosf(ang), s1 = __sinf(ang);
        float c2 = c1 * c1 - s1 * s1, s2 = 2.0f * c1 * s1;
        strig[t] = (f2){c1, s1};
        peb[t]   = (h4){(_Float16)c1, (_Float16)s1, (_Float16)c2, (_Float16)s2};

        float zc = b1[t];
#pragma unroll
        for (int zz = 0; zz < 32; ++zz)
            zc = fmaf(z[zz], W1[(10 + zz) * 64 + t], zc);

        h8 row0, row1;
#pragma unroll
        for (int k = 0; k < 8; ++k) row0[k] = (_Float16)W1[k * 64 + t];
        row1 = (h8)0;
        row1[0] = (_Float16)W1[8 * 64 + t];   // wc
        row1[1] = (_Float16)W1[9 * 64 + t];   // ws
        row1[2] = (_Float16)zc;               // bias via "1" feature
        *(h8*)&Ald[t][0] = row0;
        *(h8*)&Ald[t][8] = row1;
    }
    __syncthreads();

    // --- P2 build: 4 cells/thread ---
    {
        int base = t * 4;
        int il = base >> 5, j0 = base & 31;
        f2 ci = strig[il];
#pragma unroll
        for (int c = 0; c < 4; ++c) {
            f2 cj = strig[32 + j0 + c];
            float ctv = fmaf(ci.x, cj.x, ci.y * cj.y);
            float stv = fabsf(fmaf(ci.y, cj.x, -(ci.x * cj.y)));
            P2[base + c] = (h4){(_Float16)ctv, (_Float16)stv,
                                (_Float16)1.0f, (_Float16)0.0f};
        }
    }

    int n = lane & 31;
    int q = lane >> 5;

    // A-frags + paired w2 (per lane)
    h8 afr[2];
    h2 w2h[2][8];
#pragma unroll
    for (int H = 0; H < 2; ++H) {
        afr[H] = *(const h8*)&Ald[H * 32 + n][q * 8];
#pragma unroll
        for (int e = 0; e < 8; ++e)
            w2h[H][e] = w2p[(e & 1) + 4 * (e >> 1) + 2 * q + 16 * H];
    }
    __syncthreads();

    // --- phase 2: 64 v-groups (32 v each), 2 MFMAs per group ---
    int wv = t >> 6;
#pragma unroll 4
    for (int i = 0; i < 16; ++i) {
        int g  = wv * 16 + i;
        int o  = g >> 5;                 // orientation
        int il = g & 31;
        int cell = il * 32 + n;

        int rA = o ? (32 + n) : il;
        int rB = o ? il : (32 + n);
        const h4* pa = q ? &P2[cell] : &peb[rA];
        const h4* pb = q ? &zq : &peb[rB];

        B8 bfr;
        bfr.q[0] = *pa;
        bfr.q[1] = *pb;

        f16v a0 = __builtin_amdgcn_mfma_f32_32x32x16_f16(afr[0], bfr.v, (f16v)(0.0f), 0, 0, 0);
        f16v a1 = __builtin_amdgcn_mfma_f32_32x32x16_f16(afr[1], bfr.v, (f16v)(0.0f), 0, 0, 0);

        float ps = 0.0f;
#pragma unroll
        for (int e = 0; e < 8; ++e) {
            h2 m0 = __builtin_elementwise_max(CVTPK(a0[2 * e], a0[2 * e + 1]), (h2)0);
            ps = FDOT2(m0, w2h[0][e], ps);
            h2 m1 = __builtin_elementwise_max(CVTPK(a1[2 * e], a1[2 * e + 1]), (h2)0);
            ps = FDOT2(m1, w2h[1][e], ps);
        }
        ps += __shfl_xor(ps, 32);
        if (q == 0) S[o][il][n] = ps;
    }
    __syncthreads();

    // --- phase 3: symmetrized output + mirror (coalesced f4 stores) ---
    float b2 = b2v[0];
    {
        int il = t >> 3;
        int j0 = (t & 7) * 4;
        f4 a = *(const f4*)&S[0][il][j0];
        f4 b = *(const f4*)&S[1][il][j0];
        f4 v;
#pragma unroll
        for (int c = 0; c < 4; ++c) {
            float x = a[c] + b[c] + b2;
            if (bi == bj && il == j0 + c) x = -1e9f;
            v[c] = x;
        }
        *(f4*)&out[(size_t)(bi * 32 + il) * N + bj * 32 + j0] = v;

        if (bj > bi) {
            int jl = t >> 3;
            int i0 = (t & 7) * 4;
            f4 m;
#pragma unroll
            for (int c = 0; c < 4; ++c)
                m[c] = S[0][i0 + c][jl] + S[1][i0 + c][jl] + b2;
            *(f4*)&out[(size_t)(bj * 32 + jl) * N + bi * 32 + i0] = m;
        }
    }
}

extern "C" void kernel_launch(void* const* d_in, const int* in_sizes, int n_in,
                              void* d_out, int out_size, void* d_ws, size_t ws_size,
                              hipStream_t stream) {
    const float* z  = (const float*)d_in[0];  // [32]
    const float* s  = (const float*)d_in[1];  // [N]
    const float* W1 = (const float*)d_in[2];  // [42,64]
    const float* b1 = (const float*)d_in[3];  // [64]
    const float* W2 = (const float*)d_in[4];  // [64]
    const float* b2 = (const float*)d_in[5];  // [1]
    int N = in_sizes[1];                      // 2048

    float* out = (float*)d_out;
    int NB = N / 32;
    int nblk = NB * (NB + 1) / 2;             // 2080 for N=2048
    gd_mfma<<<nblk, 256, 0, stream>>>(z, s, W1, b1, W2, b2, out, N, NB);
}

// Round 15
// 29.012 us; speedup vs baseline: 1.4255x; 1.0014x over previous
//
#include <hip/hip_runtime.h>
#include <math.h>

#define TWO_PI_F 6.28318530717958647692f

typedef unsigned int u32;
typedef __attribute__((ext_vector_type(4))) float    f4;
typedef __attribute__((ext_vector_type(16))) float   f16v;
typedef __attribute__((ext_vector_type(2))) float    f2;
typedef __attribute__((ext_vector_type(2))) _Float16 h2;
typedef __attribute__((ext_vector_type(4))) _Float16 h4;
typedef __attribute__((ext_vector_type(8))) _Float16 h8;

union B8 { h8 v; h4 q[2]; };
union C2 { u32 w[2]; h4 v; };
union P4 { h2 a[4]; h8 v; };

#if __has_builtin(__builtin_amdgcn_fdot2)
#define FDOT2(a, b, c) __builtin_amdgcn_fdot2((a), (b), (c), false)
#else
__device__ __forceinline__ float FDOT2(h2 a, h2 b, float c) {
    return c + (float)a[0] * (float)b[0] + (float)a[1] * (float)b[1];
}
#endif

#if __has_builtin(__builtin_amdgcn_cvt_pkrtz)
__device__ __forceinline__ h2 CVTPK(float a, float b) {
    return __builtin_bit_cast(h2, __builtin_amdgcn_cvt_pkrtz(a, b));
}
#else
__device__ __forceinline__ h2 CVTPK(float a, float b) {
    return (h2){(_Float16)a, (_Float16)b};
}
#endif

// ---------------------------------------------------------------------------
// MFMA formulation (as r14: 32x32x16, K=16 exact) with three refinements:
//  - o = wv>>1 is wave-invariant; il = (wv&1)*16 + i  -> o-selects hoisted
//  - dual-stream body (il, il+8): 4 MFMAs + 2 epilogues per iter, explicit ILP
//  - 4 independent fdot2 accumulators/stream (was 1: 16-deep serial chain)
//  - P2 stored as h2 {ct,st} (4KB, was 8); constant k-slots {1,0} composed
//    from an immediate -> LDS 17.6KB -> 9 blocks/CU capacity
// 2080 upper-triangular blocks, 256 threads.
// ---------------------------------------------------------------------------
__global__ __launch_bounds__(256, 4) void gd_mfma(
    const float* __restrict__ z,  const float* __restrict__ s,
    const float* __restrict__ W1, const float* __restrict__ b1,
    const float* __restrict__ W2, const float* __restrict__ b2v,
    float* __restrict__ out, int N, int NB)
{
    __shared__ __attribute__((aligned(16))) _Float16 Ald[64][24]; // 3KB
    __shared__ __attribute__((aligned(16))) h4 peb[64];           // 512B
    __shared__ __attribute__((aligned(16))) h2 P2[1024];          // 4KB {ct,st}
    __shared__ __attribute__((aligned(16))) h2 w2p[32];           // 128B
    __shared__ __attribute__((aligned(16))) float S[2][32][36];   // 9.2KB
    __shared__ f2 strig[64];                                      // 512B

    // --- triangular block decode: u -> (bi, bj), bj >= bi ---
    int u = blockIdx.x;
    int M = 2 * NB + 1;
    float disc = (float)(M * M - 8 * u);
    int bi = (int)(((float)M - sqrtf(disc)) * 0.5f);
    if (bi < 0) bi = 0;
    if (bi > NB - 1) bi = NB - 1;
    while (bi > 0 && bi * (M - bi) / 2 > u) --bi;
    while ((bi + 1) * (M - (bi + 1)) / 2 <= u) ++bi;
    int bj = bi + (u - bi * (M - bi) / 2);

    int t    = threadIdx.x;
    int lane = t & 63;

    if (t >= 64 && t < 96) {             // paired 0.5*w2
        int r2 = t - 64;
        w2p[r2] = (h2){(_Float16)(0.5f * W2[2 * r2]),
                       (_Float16)(0.5f * W2[2 * r2 + 1])};
    }
    if (t < 64) {                        // trig + pe + V^T rows
        int grow = (t < 32) ? (bi * 32 + t) : (bj * 32 + (t - 32));
        float ang = TWO_PI_F * s[grow];
        float c1 = __cosf(ang), s1 = __sinf(ang);
        float c2 = c1 * c1 - s1 * s1, s2 = 2.0f * c1 * s1;
        strig[t] = (f2){c1, s1};
        peb[t]   = (h4){(_Float16)c1, (_Float16)s1, (_Float16)c2, (_Float16)s2};

        float zc = b1[t];
#pragma unroll
        for (int zz = 0; zz < 32; ++zz)
            zc = fmaf(z[zz], W1[(10 + zz) * 64 + t], zc);

        h8 row0, row1;
#pragma unroll
        for (int k = 0; k < 8; ++k) row0[k] = (_Float16)W1[k * 64 + t];
        row1 = (h8)0;
        row1[0] = (_Float16)W1[8 * 64 + t];   // wc
        row1[1] = (_Float16)W1[9 * 64 + t];   // ws
        row1[2] = (_Float16)zc;               // bias via "1" feature
        *(h8*)&Ald[t][0] = row0;
        *(h8*)&Ald[t][8] = row1;
    }
    __syncthreads();

    // --- P2 build: 4 cells/thread, one b128 store ---
    {
        int base = t * 4;
        int il = base >> 5, j0 = base & 31;
        f2 ci = strig[il];
        P4 pk;
#pragma unroll
        for (int c = 0; c < 4; ++c) {
            f2 cj = strig[32 + j0 + c];
            float ctv = fmaf(ci.x, cj.x, ci.y * cj.y);
            float stv = fabsf(fmaf(ci.y, cj.x, -(ci.x * cj.y)));
            pk.a[c] = CVTPK(ctv, stv);
        }
        *(h8*)&P2[base] = pk.v;
    }

    int n = lane & 31;
    int q = lane >> 5;

    // A-frags + paired w2 (per lane)
    h8 afr[2];
    h2 w2h[2][8];
#pragma unroll
    for (int H = 0; H < 2; ++H) {
        afr[H] = *(const h8*)&Ald[H * 32 + n][q * 8];
#pragma unroll
        for (int e = 0; e < 8; ++e)
            w2h[H][e] = w2p[(e & 1) + 4 * (e >> 1) + 2 * q + 16 * H];
    }
    __syncthreads();

    // --- phase 2: dual-stream MFMA loop ---
    int wv   = t >> 6;
    int o    = wv >> 1;          // orientation: wave-invariant
    int base = (wv & 1) * 16;    // il base

    h4 pe_inv = peb[32 + n];     // fixed-role pe row (invariant across iters)

#pragma unroll
    for (int i = 0; i < 8; ++i) {
        int ilA = base + i;
        int ilB = base + i + 8;

        h4 varA = peb[ilA];                        // broadcast (uniform addr)
        h4 varB = peb[ilB];
        u32 pwA = *(const u32*)&P2[ilA * 32 + n];  // conflict-free b32
        u32 pwB = *(const u32*)&P2[ilB * 32 + n];

        B8 bA, bB;
        {
            h4 pa = o ? pe_inv : varA;
            h4 pb = o ? varA : pe_inv;
            C2 cc; cc.w[0] = pwA; cc.w[1] = 0x00003C00u;   // {ct,st,1,0}
            bA.q[0] = q ? cc.v : pa;
            bA.q[1] = q ? (h4)0 : pb;
        }
        {
            h4 pa = o ? pe_inv : varB;
            h4 pb = o ? varB : pe_inv;
            C2 cc; cc.w[0] = pwB; cc.w[1] = 0x00003C00u;
            bB.q[0] = q ? cc.v : pa;
            bB.q[1] = q ? (h4)0 : pb;
        }

        f16v a0A = __builtin_amdgcn_mfma_f32_32x32x16_f16(afr[0], bA.v, (f16v)(0.0f), 0, 0, 0);
        f16v a1A = __builtin_amdgcn_mfma_f32_32x32x16_f16(afr[1], bA.v, (f16v)(0.0f), 0, 0, 0);
        f16v a0B = __builtin_amdgcn_mfma_f32_32x32x16_f16(afr[0], bB.v, (f16v)(0.0f), 0, 0, 0);
        f16v a1B = __builtin_amdgcn_mfma_f32_32x32x16_f16(afr[1], bB.v, (f16v)(0.0f), 0, 0, 0);

        float pA0 = 0.f, pA1 = 0.f, pA2 = 0.f, pA3 = 0.f;
        float pB0 = 0.f, pB1 = 0.f, pB2 = 0.f, pB3 = 0.f;
#pragma unroll
        for (int e = 0; e < 8; ++e) {
            h2 mA0 = __builtin_elementwise_max(CVTPK(a0A[2 * e], a0A[2 * e + 1]), (h2)0);
            h2 mA1 = __builtin_elementwise_max(CVTPK(a1A[2 * e], a1A[2 * e + 1]), (h2)0);
            h2 mB0 = __builtin_elementwise_max(CVTPK(a0B[2 * e], a0B[2 * e + 1]), (h2)0);
            h2 mB1 = __builtin_elementwise_max(CVTPK(a1B[2 * e], a1B[2 * e + 1]), (h2)0);
            if (e & 1) {
                pA1 = FDOT2(mA0, w2h[0][e], pA1);
                pA3 = FDOT2(mA1, w2h[1][e], pA3);
                pB1 = FDOT2(mB0, w2h[0][e], pB1);
                pB3 = FDOT2(mB1, w2h[1][e], pB3);
            } else {
                pA0 = FDOT2(mA0, w2h[0][e], pA0);
                pA2 = FDOT2(mA1, w2h[1][e], pA2);
                pB0 = FDOT2(mB0, w2h[0][e], pB0);
                pB2 = FDOT2(mB1, w2h[1][e], pB2);
            }
        }
        float psA = (pA0 + pA1) + (pA2 + pA3);
        float psB = (pB0 + pB1) + (pB2 + pB3);
        psA += __shfl_xor(psA, 32);
        psB += __shfl_xor(psB, 32);
        if (q == 0) {
            S[o][ilA][n] = psA;
            S[o][ilB][n] = psB;
        }
    }
    __syncthreads();

    // --- phase 3: symmetrized output + mirror (coalesced f4 stores) ---
    float b2 = b2v[0];
    {
        int il = t >> 3;
        int j0 = (t & 7) * 4;
        f4 a = *(const f4*)&S[0][il][j0];
        f4 b = *(const f4*)&S[1][il][j0];
        f4 v;
#pragma unroll
        for (int c = 0; c < 4; ++c) {
            float x = a[c] + b[c] + b2;
            if (bi == bj && il == j0 + c) x = -1e9f;
            v[c] = x;
        }
        *(f4*)&out[(size_t)(bi * 32 + il) * N + bj * 32 + j0] = v;

        if (bj > bi) {
            int jl = t >> 3;
            int i0 = (t & 7) * 4;
            f4 m;
#pragma unroll
            for (int c = 0; c < 4; ++c)
                m[c] = S[0][i0 + c][jl] + S[1][i0 + c][jl] + b2;
            *(f4*)&out[(size_t)(bj * 32 + jl) * N + bi * 32 + i0] = m;
        }
    }
}

extern "C" void kernel_launch(void* const* d_in, const int* in_sizes, int n_in,
                              void* d_out, int out_size, void* d_ws, size_t ws_size,
                              hipStream_t stream) {
    const float* z  = (const float*)d_in[0];  // [32]
    const float* s  = (const float*)d_in[1];  // [N]
    const float* W1 = (const float*)d_in[2];  // [42,64]
    const float* b1 = (const float*)d_in[3];  // [64]
    const float* W2 = (const float*)d_in[4];  // [64]
    const float* b2 = (const float*)d_in[5];  // [1]
    int N = in_sizes[1];                      // 2048

    float* out = (float*)d_out;
    int NB = N / 32;
    int nblk = NB * (NB + 1) / 2;             // 2080 for N=2048
    gd_mfma<<<nblk, 256, 0, stream>>>(z, s, W1, b1, W2, b2, out, N, NB);
}